// Round 2
// baseline (95.861 us; speedup 1.0000x reference)
//
#include <hip/hip_runtime.h>
#include <hip/hip_bf16.h>

typedef __bf16 bf16;
typedef __bf16 bf16x4 __attribute__((ext_vector_type(4)));
typedef __bf16 bf16x8 __attribute__((ext_vector_type(8)));
typedef float  f32x4  __attribute__((ext_vector_type(4)));

#define HID   128
#define BSZ   8
#define CDIM  512
#define QDIM  64

// workspace layout (bytes)
#define WEFF_OFF 0u          // 512 * 128*128 bf16 = 16,777,216 B
#define HBF_OFF  16777216u   // 8*512*128 bf16    =  1,048,576 B
#define BIAS_OFF 17825792u   // 512 * 128 fp32    =    262,144 B

// ---------------------------------------------------------------------------
// Prep: blocks 0..127 build W_eff[b,q,k,d] = w_h[k,d] + u[b,q,d]*w_hu[k,d]
//       (bf16) and bias[b,q,k] = b1[k] + u.w_u[k] (fp32 exact).
//       Blocks 128..191 convert h fp32 -> bf16.
// Reads w1 exactly 16x total (vs 512x in the fused version).
// ---------------------------------------------------------------------------
__global__ __launch_bounds__(256)
void prep_kernel(const float* __restrict__ hptr,
                 const float* __restrict__ uptr,
                 const float* __restrict__ w1,
                 const float* __restrict__ b1,
                 char* __restrict__ ws)
{
    __shared__ float u_sh[QDIM * 132];  // +4 pad: breaks 128-stride bank alias
    __shared__ float w_sh[8 * 388];     // +4 pad: breaks 384-stride bank alias
    const int t   = threadIdx.x;
    const int blk = blockIdx.x;

    if (blk < 128) {
        const int b  = blk >> 4;
        const int k0 = (blk & 15) * 8;
        const float* ub = uptr + b * QDIM * HID;

        #pragma unroll
        for (int i = 0; i < 8; ++i) {            // u[b]: 2048 float4, coalesced
            const int f4 = i * 256 + t;
            const int q  = f4 >> 5, c4 = f4 & 31;
            float4 v = *(const float4*)(ub + f4 * 4);
            *(float4*)&u_sh[q * 132 + c4 * 4] = v;
        }
        #pragma unroll
        for (int i = 0; i < 3; ++i) {            // w1 rows k0..k0+7: 768 float4
            const int f4 = i * 256 + t;
            const int r = f4 / 96, c4 = f4 % 96;
            float4 v = *(const float4*)(w1 + (k0 + r) * 384 + c4 * 4);
            *(float4*)&w_sh[r * 388 + c4 * 4] = v;
        }
        __syncthreads();

        bf16* weff = (bf16*)(ws + WEFF_OFF);
        #pragma unroll 4
        for (int i = 0; i < 64; ++i) {           // 16384 8-B chunks, coalesced
            const int flat = i * 256 + t;
            const int row = flat >> 5, ch = flat & 31;
            const int q = row >> 3, kk = row & 7, d = ch * 4;
            const float* uu  = &u_sh[q * 132 + d];
            const float* wh  = &w_sh[kk * 388 + d];
            const float* whu = &w_sh[kk * 388 + 256 + d];
            bf16x4 o;
            o[0] = (bf16)(wh[0] + uu[0] * whu[0]);
            o[1] = (bf16)(wh[1] + uu[1] * whu[1]);
            o[2] = (bf16)(wh[2] + uu[2] * whu[2]);
            o[3] = (bf16)(wh[3] + uu[3] * whu[3]);
            *(bf16x4*)&weff[(((b * QDIM + q) * HID) + k0 + kk) * HID + d] = o;
        }

        float* bias = (float*)(ws + BIAS_OFF);
        #pragma unroll
        for (int r = 0; r < 2; ++r) {            // 512 dot products over d=128
            const int p = r * 256 + t;
            const int q = p >> 3, kk = p & 7;
            const float* uu = &u_sh[q * 132];
            const float* wu = &w_sh[kk * 388 + 128];
            float acc = 0.f;
            #pragma unroll 8
            for (int d = 0; d < 128; d += 4) {
                f32x4 a = *(const f32x4*)&uu[d];
                f32x4 w = *(const f32x4*)&wu[d];
                acc += a[0]*w[0] + a[1]*w[1] + a[2]*w[2] + a[3]*w[3];
            }
            bias[(b * QDIM + q) * HID + k0 + kk] = b1[k0 + kk] + acc;
        }
    } else {
        const int wg = blk - 128;                // h fp32 -> bf16, coalesced
        bf16* hbf = (bf16*)(ws + HBF_OFF);
        #pragma unroll
        for (int i = 0; i < 8; ++i) {
            const int f4 = wg * 2048 + i * 256 + t;
            float4 v = *(const float4*)(hptr + f4 * 4);
            bf16x4 o;
            o[0] = (bf16)v.x; o[1] = (bf16)v.y; o[2] = (bf16)v.z; o[3] = (bf16)v.w;
            *(bf16x4*)&hbf[f4 * 4] = o;
        }
    }
}

// ---------------------------------------------------------------------------
// Main: one WG per (b,q). Zero LDS, zero barriers. B-fragments (W_eff) cached
// in 128 VGPRs for the WG lifetime; A-fragments streamed from L2-resident
// h_bf16. Fused epilogue: relu(+bias) . w2, 16-lane shuffle reduce, relu(+b2).
// ---------------------------------------------------------------------------
__global__ __launch_bounds__(256, 2)
void main_kernel(const char* __restrict__ ws,
                 const float* __restrict__ w2,
                 const float* __restrict__ b2,
                 float* __restrict__ out)
{
    const int t    = threadIdx.x;
    const int bi   = blockIdx.x >> 6;
    const int qi   = blockIdx.x & 63;
    const int lane = t & 63;
    const int wv   = t >> 6;      // wave 0..3 -> c rows [wv*128, wv*128+128)
    const int col  = lane & 15;
    const int quad = lane >> 4;

    const bf16*  weff = (const bf16*)(ws + WEFF_OFF) + (size_t)(bi * QDIM + qi) * (HID * HID);
    const float* bias = (const float*)(ws + BIAS_OFF) + (bi * QDIM + qi) * HID;
    const bf16*  hbf  = (const bf16*)(ws + HBF_OFF) + (size_t)bi * CDIM * HID;

    // B fragments: B[kdim = quad*8+j][n-col] = W_eff[n*16+col][kdim]
    bf16x8 bfrag[4][8];
    #pragma unroll
    for (int ks = 0; ks < 4; ++ks)
        #pragma unroll
        for (int n = 0; n < 8; ++n)
            bfrag[ks][n] = *(const bf16x8*)&weff[(n * 16 + col) * HID + ks * 32 + quad * 8];

    float bias_l[8], w2_l[8];
    #pragma unroll
    for (int n = 0; n < 8; ++n) {
        bias_l[n] = bias[n * 16 + col];
        w2_l[n]   = w2[n * 16 + col];
    }
    const float b2v = b2[0];

    float* obase = out + (bi * CDIM) * QDIM + qi;

    #pragma unroll 2
    for (int rt = 0; rt < 8; ++rt) {
        const int c0 = wv * 128 + rt * 16;

        f32x4 acc[8];
        #pragma unroll
        for (int n = 0; n < 8; ++n) acc[n] = (f32x4){0.f, 0.f, 0.f, 0.f};

        #pragma unroll
        for (int ks = 0; ks < 4; ++ks) {
            // A[m = col][kdim = quad*8+j] straight from global (L2-resident)
            bf16x8 a = *(const bf16x8*)&hbf[(c0 + col) * HID + ks * 32 + quad * 8];
            #pragma unroll
            for (int n = 0; n < 8; ++n)
                acc[n] = __builtin_amdgcn_mfma_f32_16x16x32_bf16(a, bfrag[ks][n], acc[n], 0, 0, 0);
        }

        // epilogue: D row = quad*4 + reg, colk = n*16 + col
        float s0 = 0.f, s1 = 0.f, s2 = 0.f, s3 = 0.f;
        #pragma unroll
        for (int n = 0; n < 8; ++n) {
            const float bl = bias_l[n], wl = w2_l[n];
            s0 += fmaxf(acc[n][0] + bl, 0.f) * wl;
            s1 += fmaxf(acc[n][1] + bl, 0.f) * wl;
            s2 += fmaxf(acc[n][2] + bl, 0.f) * wl;
            s3 += fmaxf(acc[n][3] + bl, 0.f) * wl;
        }
        #pragma unroll
        for (int off = 1; off < 16; off <<= 1) {
            s0 += __shfl_xor(s0, off, 64);
            s1 += __shfl_xor(s1, off, 64);
            s2 += __shfl_xor(s2, off, 64);
            s3 += __shfl_xor(s3, off, 64);
        }
        if (col < 4) {
            const float sv = col == 0 ? s0 : col == 1 ? s1 : col == 2 ? s2 : s3;
            const int crow = c0 + quad * 4 + col;
            obase[crow * QDIM] = fmaxf(sv + b2v, 0.f);
        }
    }
}

extern "C" void kernel_launch(void* const* d_in, const int* in_sizes, int n_in,
                              void* d_out, int out_size, void* d_ws, size_t ws_size,
                              hipStream_t stream) {
    const float* h  = (const float*)d_in[0];
    const float* u  = (const float*)d_in[1];
    const float* w1 = (const float*)d_in[2];
    const float* b1 = (const float*)d_in[3];
    const float* w2 = (const float*)d_in[4];
    const float* b2 = (const float*)d_in[5];
    float* out = (float*)d_out;
    char* ws = (char*)d_ws;

    prep_kernel<<<dim3(192), dim3(256), 0, stream>>>(h, u, w1, b1, ws);
    main_kernel<<<dim3(BSZ * QDIM), dim3(256), 0, stream>>>(ws, w2, b2, out);
}